// Round 4
// baseline (5186.980 us; speedup 1.0000x reference)
//
#include <hip/hip_runtime.h>

#define TPB 512
#define BM 64
#define AS 128   // activation row stride in floats

// ===========================================================================
// CSR build: count -> block scan -> fixup -> scatter. Rebuilt every call.
// ===========================================================================
__global__ void count_kernel(const int* __restrict__ ei, int* __restrict__ cnt, int E)
{
    int e = blockIdx.x * blockDim.x + threadIdx.x;
    if (e >= E) return;
    atomicAdd(cnt + ei[E + e], 1);
}

__global__ void scan_blocks(const int* __restrict__ cnt, int* __restrict__ rs,
                            int* __restrict__ part, int N)
{
    __shared__ int sums[256];
    int t = threadIdx.x;
    int base = blockIdx.x * 2048 + t * 8;
    int v[8], s = 0;
#pragma unroll
    for (int i = 0; i < 8; i++) { int idx = base + i; v[i] = (idx < N) ? cnt[idx] : 0; s += v[i]; }
    sums[t] = s;
    __syncthreads();
    for (int off = 1; off < 256; off <<= 1) {
        int x = (t >= off) ? sums[t - off] : 0;
        __syncthreads();
        if (t >= off) sums[t] += x;
        __syncthreads();
    }
    int run = (t == 0) ? 0 : sums[t - 1];
#pragma unroll
    for (int i = 0; i < 8; i++) { int idx = base + i; if (idx < N) rs[idx] = run; run += v[i]; }
    if (t == 255) part[blockIdx.x] = sums[255];
}

__global__ void scan_part(int* __restrict__ part, int nb)
{
    __shared__ int sums[256];
    int t = threadIdx.x;
    int base = t * 8;
    int v[8], s = 0;
#pragma unroll
    for (int i = 0; i < 8; i++) { int idx = base + i; v[i] = (idx < nb) ? part[idx] : 0; s += v[i]; }
    sums[t] = s;
    __syncthreads();
    for (int off = 1; off < 256; off <<= 1) {
        int x = (t >= off) ? sums[t - off] : 0;
        __syncthreads();
        if (t >= off) sums[t] += x;
        __syncthreads();
    }
    int run = (t == 0) ? 0 : sums[t - 1];
#pragma unroll
    for (int i = 0; i < 8; i++) { int idx = base + i; if (idx < nb) part[idx] = run; run += v[i]; }
}

__global__ void scan_fixup(int* __restrict__ rs, int* __restrict__ cursor,
                           const int* __restrict__ part, int N, int E)
{
    int i = blockIdx.x * blockDim.x + threadIdx.x;
    if (i < N) { int v = rs[i] + part[i >> 11]; rs[i] = v; cursor[i] = v; }
    if (i == 0) rs[N] = E;
}

__global__ void scatter_kernel(const int* __restrict__ ei, int* __restrict__ cursor,
                               int* __restrict__ col, int E)
{
    int e = blockIdx.x * blockDim.x + threadIdx.x;
    if (e >= E) return;
    int d = ei[E + e];
    int p = atomicAdd(cursor + d, 1);
    col[p] = ei[e];
}

// ===========================================================================
// In-place GEMM layer with double-buffered 8KB weight chunks and register
// prefetch: one barrier per chunk, global latency hidden under the k-loop.
//   act[r][0:C] = f(sum_k act[r][k]*W[k][c] + scale(r)*bias[c])
// ===========================================================================
template<int CPT>
__device__ __forceinline__ void gemm_layer(
    float* __restrict__ act, const float* __restrict__ Wg,
    const float* __restrict__ bias_g, const float* __restrict__ ldeg,
    float* __restrict__ wbuf,                 // 2*2048 floats
    int K_real, int K_pad, bool relu,
    float* __restrict__ state_g, long base, int n)
{
    constexpr int C = CPT * 32;
    constexpr int RPC = 2048 / C;             // rows per 8KB chunk
    const int tid = threadIdx.x;
    const int tx = tid & 31;
    const int ty = tid >> 5;
    const int r0 = ty * 4;
    const int c0 = tx * CPT;
    const int nc = (K_pad + RPC - 1) / RPC;

    // per-thread 16B slice of a chunk
    const int fo = tid * 4;
    const int lr = fo / C;                    // local row within chunk
    const int lc = fo - lr * C;

    auto ldchunk = [&](int c) -> float4 {
        int gk = c * RPC + lr;
        float4 v = make_float4(0.f, 0.f, 0.f, 0.f);
        if (gk < K_real) v = *(const float4*)(Wg + (long)gk * C + lc);
        return v;
    };

    float acc[4][CPT];
#pragma unroll
    for (int i = 0; i < 4; i++)
#pragma unroll
        for (int j = 0; j < CPT; j++) acc[i][j] = 0.0f;

    // prologue: chunk0 -> wbuf0, prefetch chunk1
    float4 pfA = ldchunk(0), pfB;
    *(float4*)(wbuf + fo) = pfA;
    if (nc > 1) pfB = ldchunk(1);
    __syncthreads();

    for (int c = 0; c < nc; ++c) {
        const float* wc = wbuf + (c & 1) * 2048;
        const int kb = c * RPC;
        int rows = K_pad - kb; if (rows > RPC) rows = RPC;

        for (int k = 0; k < rows; k += 4) {
            float4 a0 = *(const float4*)(act + (r0 + 0) * AS + kb + k);
            float4 a1 = *(const float4*)(act + (r0 + 1) * AS + kb + k);
            float4 a2 = *(const float4*)(act + (r0 + 2) * AS + kb + k);
            float4 a3 = *(const float4*)(act + (r0 + 3) * AS + kb + k);
#pragma unroll
            for (int kk = 0; kk < 4; kk++) {
                float b[CPT];
                if (CPT == 4) {
                    float4 bv = *(const float4*)(wc + (k + kk) * C + c0);
                    b[0] = bv.x; b[1] = bv.y; b[2] = bv.z; b[3] = bv.w;
                } else {
                    float2 bv = *(const float2*)(wc + (k + kk) * C + c0);
                    b[0] = bv.x; b[1] = bv.y;
                }
                float av[4];
                av[0] = ((const float*)&a0)[kk];
                av[1] = ((const float*)&a1)[kk];
                av[2] = ((const float*)&a2)[kk];
                av[3] = ((const float*)&a3)[kk];
#pragma unroll
                for (int i = 0; i < 4; i++)
#pragma unroll
                    for (int j = 0; j < CPT; j++)
                        acc[i][j] = fmaf(av[i], b[j], acc[i][j]);
            }
        }

        // write next chunk into the other buffer (everyone done reading it:
        // its last readers passed the barrier ending iteration c-1)
        if (c + 1 < nc) {
            float4 w = ((c + 1) & 1) ? pfB : pfA;
            *(float4*)(wbuf + ((c + 1) & 1) * 2048 + fo) = w;
        }
        // prefetch chunk c+2 into the register set just freed
        if (c + 2 < nc) {
            if (c & 1) pfB = ldchunk(c + 2); else pfA = ldchunk(c + 2);
        }
        __syncthreads();   // chunk c+1 visible; all waves past k-loop of chunk c
    }

    // all reads of act done (barrier above) -> write outputs in place
#pragma unroll
    for (int i = 0; i < 4; i++) {
        int r = r0 + i;
        float scale = ldeg ? ldeg[r] : 1.0f;
        float vv[CPT];
#pragma unroll
        for (int j = 0; j < CPT; j++) {
            float v = acc[i][j] + scale * bias_g[c0 + j];
            if (relu) v = fmaxf(v, 0.0f);
            vv[j] = v;
        }
        if (CPT == 4) *(float4*)(act + r * AS + c0) = make_float4(vv[0], vv[1], vv[2], vv[3]);
        else          *(float2*)(act + r * AS + c0) = make_float2(vv[0], vv[1]);
        if (state_g != nullptr && base + r < n) {
            if (CPT == 4) *(float4*)(state_g + (base + r) * 64 + c0) = make_float4(vv[0], vv[1], vv[2], vv[3]);
            else          *(float2*)(state_g + (base + r) * 64 + c0) = make_float2(vv[0], vv[1]);
        }
    }
    __syncthreads();
}

// ===========================================================================
// Fused per-64-node-tile: CSR gather -> layer0 -> update MLP -> predictor.
// LDS ~49KB -> 3 blocks/CU.
// ===========================================================================
template<int K0>
__global__ __launch_bounds__(TPB, 6)
void fused_kernel(const int* __restrict__ rs, const int* __restrict__ col,
                  const float* __restrict__ srcdat, int nvar,
                  const float* __restrict__ xg,
                  const float* __restrict__ W0, const float* __restrict__ b0,
                  const float* __restrict__ uW1, const float* __restrict__ ub1,
                  const float* __restrict__ uW2, const float* __restrict__ ub2,
                  const float* __restrict__ uW3, const float* __restrict__ ub3,
                  const float* __restrict__ pW1, const float* __restrict__ pb1,
                  const float* __restrict__ pW2, const float* __restrict__ pb2,
                  const float* __restrict__ pW3, const float* __restrict__ pb3,
                  float* __restrict__ state_g, float* __restrict__ outg, int n)
{
    __shared__ float act[BM * AS];
    __shared__ float wbuf[2 * 2048];
    __shared__ float ldeg[BM];

    const int tid = threadIdx.x;
    const long base = (long)blockIdx.x * BM;
    const int nvar2 = 2 * nvar;
    const int wave = tid >> 6;
    const int lane = tid & 63;

    // ---- CSR gather into act[:, 0:K0]; deg -> ldeg
    if constexpr (K0 == 64) {
        for (int i = 0; i < 8; i++) {
            int node = wave * 8 + i;
            long g = base + node;
            int d0 = 0, d1 = 0;
            if (g < n) { d0 = rs[g]; d1 = rs[g + 1]; }
            float acc = 0.0f;
            int e = d0;
            for (; e + 4 <= d1; e += 4) {
                int s0 = col[e], s1 = col[e + 1], s2 = col[e + 2], s3 = col[e + 3];
                float a0 = (s0 < nvar2) ? srcdat[(long)s0 * 64 + lane] : 0.0f;
                float a1 = (s1 < nvar2) ? srcdat[(long)s1 * 64 + lane] : 0.0f;
                float a2 = (s2 < nvar2) ? srcdat[(long)s2 * 64 + lane] : 0.0f;
                float a3 = (s3 < nvar2) ? srcdat[(long)s3 * 64 + lane] : 0.0f;
                acc += a0 + a1 + a2 + a3;
            }
            for (; e < d1; e++) {
                int s = col[e];
                if (s < nvar2) acc += srcdat[(long)s * 64 + lane];
            }
            act[node * AS + lane] = acc;
            if (lane == 0) ldeg[node] = (float)(d1 - d0);
        }
    } else {
        const int f = lane & 15, sub = lane >> 4;
        for (int i = 0; i < 2; i++) {
            int node = wave * 8 + i * 4 + sub;
            long g = base + node;
            int d0 = 0, d1 = 0;
            if (g < n) { d0 = rs[g]; d1 = rs[g + 1]; }
            float acc = 0.0f;
            int e = d0;
            for (; e + 2 <= d1; e += 2) {
                int s0 = col[e], s1 = col[e + 1];
                float a0 = 0.0f, a1 = 0.0f;
                if (s0 < nvar2) {
                    a0 = srcdat[(long)((s0 < nvar) ? s0 : s0 - nvar) * 16 + f];
                    if (s0 >= nvar) a0 = -a0;
                }
                if (s1 < nvar2) {
                    a1 = srcdat[(long)((s1 < nvar) ? s1 : s1 - nvar) * 16 + f];
                    if (s1 >= nvar) a1 = -a1;
                }
                acc += a0 + a1;
            }
            for (; e < d1; e++) {
                int s = col[e];
                if (s < nvar2) {
                    float a = srcdat[(long)((s < nvar) ? s : s - nvar) * 16 + f];
                    acc += (s < nvar) ? a : -a;
                }
            }
            act[node * AS + f] = acc;
            if (f == 0) ldeg[node] = (float)(d1 - d0);
        }
    }
    __syncthreads();

    // ---- layer0: msg = gather@W0 + deg*b0 (reads cols 0:K0, writes 0:64)
    gemm_layer<2>(act, W0, b0, ldeg, wbuf, K0, K0, false, nullptr, base, n);

    // stage x -> cols 64..66, zero col 67 (visible after next layer's prologue barrier)
    for (int idx = tid; idx < BM * 3; idx += TPB) {
        int node = idx / 3, j = idx % 3;
        float v = (base + node < n) ? xg[(base + node) * 3 + j] : 0.0f;
        act[node * AS + 64 + j] = v;
    }
    if (tid < BM) act[tid * AS + 67] = 0.0f;

    // ---- update MLP
    gemm_layer<4>(act, uW1, ub1, nullptr, wbuf, 67, 68, true, nullptr, base, n);
    gemm_layer<4>(act, uW2, ub2, nullptr, wbuf, 128, 128, true, nullptr, base, n);
    gemm_layer<2>(act, uW3, ub3, nullptr, wbuf, 128, 128, false, state_g, base, n);

    // ---- predictor MLP
    gemm_layer<4>(act, pW1, pb1, nullptr, wbuf, 64, 64, true, nullptr, base, n);
    gemm_layer<4>(act, pW2, pb2, nullptr, wbuf, 128, 128, true, nullptr, base, n);

    // ---- predictor layer3: 128 -> 2
    for (int i = tid; i < 64; i += TPB)
        ((float4*)wbuf)[i] = ((const float4*)pW3)[i];
    __syncthreads();
    if (tid < 128) {
        int r = tid >> 1, c = tid & 1;
        float acc = pb3[c];
        for (int k = 0; k < 128; k += 4) {
            float4 a = *(const float4*)(act + r * AS + k);
            acc = fmaf(a.x, wbuf[(k + 0) * 2 + c], acc);
            acc = fmaf(a.y, wbuf[(k + 1) * 2 + c], acc);
            acc = fmaf(a.z, wbuf[(k + 2) * 2 + c], acc);
            acc = fmaf(a.w, wbuf[(k + 3) * 2 + c], acc);
        }
        if (base + r < n) outg[(base + r) * 2 + c] = acc;
    }
}

// ===========================================================================
extern "C" void kernel_launch(void* const* d_in, const int* in_sizes, int n_in,
                              void* d_out, int out_size, void* d_ws, size_t ws_size,
                              hipStream_t stream)
{
    const float* x    = (const float*)d_in[0];
    const int*   ei   = (const int*)d_in[1];
    // d_in[2] = gate_type: fixed ordering [VAR*nvar, NEGVAR*nvar, CLAUSE*ncla]
    const float* posr = (const float*)d_in[3];
    const float* Wr   = (const float*)d_in[4];
    const float* br   = (const float*)d_in[5];
    const float* Wc   = (const float*)d_in[6];
    const float* bc   = (const float*)d_in[7];
    const float* uW1  = (const float*)d_in[8];
    const float* ub1  = (const float*)d_in[9];
    const float* uW2  = (const float*)d_in[10];
    const float* ub2  = (const float*)d_in[11];
    const float* uW3  = (const float*)d_in[12];
    const float* ub3  = (const float*)d_in[13];
    const float* pW1  = (const float*)d_in[14];
    const float* pb1  = (const float*)d_in[15];
    const float* pW2  = (const float*)d_in[16];
    const float* pb2  = (const float*)d_in[17];
    const float* pW3  = (const float*)d_in[18];
    const float* pb3  = (const float*)d_in[19];

    const int N     = in_sizes[0] / 3;
    const int E     = in_sizes[1] / 2;
    const int nvar  = in_sizes[3] / 16;
    const int nvar2 = 2 * nvar;
    const int ncla  = N - nvar2;

    // workspace carve-out
    int* cnt    = (int*)d_ws;              // [N]
    int* rs     = cnt + N;                 // [N+1]
    int* cursor = rs + N + 1;              // [N]
    int* part   = cursor + N;              // [2048]
    int* col    = part + 2048;             // [E]
    size_t foff = ((size_t)(col + E - (int*)d_ws) + 3) & ~(size_t)3;
    float* state = (float*)d_ws + foff;    // [2nvar*64]

    hipMemsetAsync(cnt, 0, (size_t)N * sizeof(int), stream);

    const int nb = (N + 2047) / 2048;
    count_kernel<<<(E + 255) / 256, 256, 0, stream>>>(ei, cnt, E);
    scan_blocks<<<nb, 256, 0, stream>>>(cnt, rs, part, N);
    scan_part<<<1, 256, 0, stream>>>(part, nb);
    scan_fixup<<<(N + 255) / 256, 256, 0, stream>>>(rs, cursor, part, N, E);
    scatter_kernel<<<(E + 255) / 256, 256, 0, stream>>>(ei, cursor, col, E);

    {   // var + negvar partitions (gather pos_random via CSR)
        int blocks = (nvar2 + BM - 1) / BM;
        fused_kernel<16><<<blocks, TPB, 0, stream>>>(
            rs, col, posr, nvar, x, Wr, br,
            uW1, ub1, uW2, ub2, uW3, ub3,
            pW1, pb1, pW2, pb2, pW3, pb3,
            state, (float*)d_out, nvar2);
    }

    {   // clause partition (gather state via CSR, rows offset by 2nvar)
        int blocks = (ncla + BM - 1) / BM;
        fused_kernel<64><<<blocks, TPB, 0, stream>>>(
            rs + nvar2, col, state, nvar, x + (size_t)nvar2 * 3, Wc, bc,
            uW1, ub1, uW2, ub2, uW3, ub3,
            pW1, pb1, pW2, pb2, pW3, pb3,
            nullptr, (float*)d_out + (size_t)nvar2 * 2, ncla);
    }
}

// Round 5
// 4419.368 us; speedup vs baseline: 1.1737x; 1.1737x over previous
//
#include <hip/hip_runtime.h>

#define TPB 512
#define BM 64
#define AS 128   // activation row stride in floats

// ===========================================================================
// CSR build: count -> block scan -> fixup -> scatter. Rebuilt every call.
// ===========================================================================
__global__ void count_kernel(const int* __restrict__ ei, int* __restrict__ cnt, int E)
{
    int e = blockIdx.x * blockDim.x + threadIdx.x;
    if (e >= E) return;
    atomicAdd(cnt + ei[E + e], 1);
}

__global__ void scan_blocks(const int* __restrict__ cnt, int* __restrict__ rs,
                            int* __restrict__ part, int N)
{
    __shared__ int sums[256];
    int t = threadIdx.x;
    int base = blockIdx.x * 2048 + t * 8;
    int v[8], s = 0;
#pragma unroll
    for (int i = 0; i < 8; i++) { int idx = base + i; v[i] = (idx < N) ? cnt[idx] : 0; s += v[i]; }
    sums[t] = s;
    __syncthreads();
    for (int off = 1; off < 256; off <<= 1) {
        int x = (t >= off) ? sums[t - off] : 0;
        __syncthreads();
        if (t >= off) sums[t] += x;
        __syncthreads();
    }
    int run = (t == 0) ? 0 : sums[t - 1];
#pragma unroll
    for (int i = 0; i < 8; i++) { int idx = base + i; if (idx < N) rs[idx] = run; run += v[i]; }
    if (t == 255) part[blockIdx.x] = sums[255];
}

__global__ void scan_part(int* __restrict__ part, int nb)
{
    __shared__ int sums[256];
    int t = threadIdx.x;
    int base = t * 8;
    int v[8], s = 0;
#pragma unroll
    for (int i = 0; i < 8; i++) { int idx = base + i; v[i] = (idx < nb) ? part[idx] : 0; s += v[i]; }
    sums[t] = s;
    __syncthreads();
    for (int off = 1; off < 256; off <<= 1) {
        int x = (t >= off) ? sums[t - off] : 0;
        __syncthreads();
        if (t >= off) sums[t] += x;
        __syncthreads();
    }
    int run = (t == 0) ? 0 : sums[t - 1];
#pragma unroll
    for (int i = 0; i < 8; i++) { int idx = base + i; if (idx < nb) part[idx] = run; run += v[i]; }
}

__global__ void scan_fixup(int* __restrict__ rs, int* __restrict__ cursor,
                           const int* __restrict__ part, int N, int E)
{
    int i = blockIdx.x * blockDim.x + threadIdx.x;
    if (i < N) { int v = rs[i] + part[i >> 11]; rs[i] = v; cursor[i] = v; }
    if (i == 0) rs[N] = E;
}

__global__ void scatter_kernel(const int* __restrict__ ei, int* __restrict__ cursor,
                               int* __restrict__ col, int E)
{
    int e = blockIdx.x * blockDim.x + threadIdx.x;
    if (e >= E) return;
    int d = ei[E + e];
    int p = atomicAdd(cursor + d, 1);
    col[p] = ei[e];
}

// ===========================================================================
// FMA over one weight chunk resident in LDS (rows x C), acc += act_block * W
// ===========================================================================
template<int CPT>
__device__ __forceinline__ void chunk_fma(const float* __restrict__ act,
                                          const float* __restrict__ wc,
                                          int kb, int rows, int r0, int c0,
                                          float (&acc)[4][CPT])
{
    constexpr int C = CPT * 32;
    for (int k = 0; k < rows; k += 4) {
        float4 a0 = *(const float4*)(act + (r0 + 0) * AS + kb + k);
        float4 a1 = *(const float4*)(act + (r0 + 1) * AS + kb + k);
        float4 a2 = *(const float4*)(act + (r0 + 2) * AS + kb + k);
        float4 a3 = *(const float4*)(act + (r0 + 3) * AS + kb + k);
#pragma unroll
        for (int kk = 0; kk < 4; kk++) {
            float b[CPT];
            if (CPT == 4) {
                float4 bv = *(const float4*)(wc + (k + kk) * C + c0);
                b[0] = bv.x; b[1] = bv.y; b[2] = bv.z; b[3] = bv.w;
            } else {
                float2 bv = *(const float2*)(wc + (k + kk) * C + c0);
                b[0] = bv.x; b[1] = bv.y;
            }
            float av[4];
            av[0] = ((const float*)&a0)[kk];
            av[1] = ((const float*)&a1)[kk];
            av[2] = ((const float*)&a2)[kk];
            av[3] = ((const float*)&a3)[kk];
#pragma unroll
            for (int i = 0; i < 4; i++)
#pragma unroll
                for (int j = 0; j < CPT; j++)
                    acc[i][j] = fmaf(av[i], b[j], acc[i][j]);
        }
    }
}

// ===========================================================================
// In-place GEMM layer, double-buffered 8KB weight chunks, register prefetch.
// Chunk loop unrolled by 2 so pfA/pfB references are compile-time static.
// One barrier per chunk; global-load latency hidden under the k-loop.
// ===========================================================================
template<int CPT>
__device__ __forceinline__ void gemm_layer(
    float* __restrict__ act, const float* __restrict__ Wg,
    const float* __restrict__ bias_g, const float* __restrict__ ldeg,
    float* __restrict__ wbuf,                 // 2*2048 floats
    int K_real, int K_pad, bool relu,
    float* __restrict__ state_g, long base, int n)
{
    constexpr int C = CPT * 32;
    constexpr int RPC = 2048 / C;             // rows per 8KB chunk
    const int tid = threadIdx.x;
    const int tx = tid & 31;
    const int ty = tid >> 5;
    const int r0 = ty * 4;
    const int c0 = tx * CPT;
    const int nc = (K_pad + RPC - 1) / RPC;

    // per-thread 16B slice of a chunk
    const int fo = tid * 4;
    const int lr = fo / C;
    const int lc = fo - lr * C;

    float acc[4][CPT];
#pragma unroll
    for (int i = 0; i < 4; i++)
#pragma unroll
        for (int j = 0; j < CPT; j++) acc[i][j] = 0.0f;

    // prologue: chunk0 -> wbuf0; chunk1 -> pfB
    float4 pfA, pfB;
    {
        int gk = lr;
        pfA = make_float4(0.f, 0.f, 0.f, 0.f);
        if (gk < K_real) pfA = *(const float4*)(Wg + (long)gk * C + lc);
        *(float4*)(wbuf + fo) = pfA;
        if (nc > 1) {
            gk = RPC + lr;
            pfB = make_float4(0.f, 0.f, 0.f, 0.f);
            if (gk < K_real) pfB = *(const float4*)(Wg + (long)gk * C + lc);
        }
    }
    __syncthreads();

    for (int c = 0; c < nc; c += 2) {
        {   // even chunk: compute on wbuf0
            int kb = c * RPC;
            int rows = K_pad - kb; if (rows > RPC) rows = RPC;
            chunk_fma<CPT>(act, wbuf, kb, rows, r0, c0, acc);
            if (c + 1 < nc) *(float4*)(wbuf + 2048 + fo) = pfB;
            if (c + 2 < nc) {
                int gk = (c + 2) * RPC + lr;
                pfA = make_float4(0.f, 0.f, 0.f, 0.f);
                if (gk < K_real) pfA = *(const float4*)(Wg + (long)gk * C + lc);
            }
            __syncthreads();
        }
        if (c + 1 < nc) {   // odd chunk: compute on wbuf1
            int kb = (c + 1) * RPC;
            int rows = K_pad - kb; if (rows > RPC) rows = RPC;
            chunk_fma<CPT>(act, wbuf + 2048, kb, rows, r0, c0, acc);
            if (c + 2 < nc) *(float4*)(wbuf + fo) = pfA;
            if (c + 3 < nc) {
                int gk = (c + 3) * RPC + lr;
                pfB = make_float4(0.f, 0.f, 0.f, 0.f);
                if (gk < K_real) pfB = *(const float4*)(Wg + (long)gk * C + lc);
            }
            __syncthreads();
        }
    }

    // all reads of act done (barrier above) -> write outputs in place
#pragma unroll
    for (int i = 0; i < 4; i++) {
        int r = r0 + i;
        float scale = ldeg ? ldeg[r] : 1.0f;
        float vv[CPT];
#pragma unroll
        for (int j = 0; j < CPT; j++) {
            float v = acc[i][j] + scale * bias_g[c0 + j];
            if (relu) v = fmaxf(v, 0.0f);
            vv[j] = v;
        }
        if (CPT == 4) *(float4*)(act + r * AS + c0) = make_float4(vv[0], vv[1], vv[2], vv[3]);
        else          *(float2*)(act + r * AS + c0) = make_float2(vv[0], vv[1]);
        if (state_g != nullptr && base + r < n) {
            if (CPT == 4) *(float4*)(state_g + (base + r) * 64 + c0) = make_float4(vv[0], vv[1], vv[2], vv[3]);
            else          *(float2*)(state_g + (base + r) * 64 + c0) = make_float2(vv[0], vv[1]);
        }
    }
    __syncthreads();
}

// ===========================================================================
// Fused per-64-node-tile: CSR gather -> layer0 -> update MLP -> predictor.
// LDS ~49KB -> 3 blocks/CU. launch_bounds kept loose: a tight min-occupancy
// hint (round 4: (512,6)) capped VGPRs at 40 and spilled acc to scratch
// (10.7 GB/dispatch scratch traffic). (512,2) caps at >=512: no spill.
// ===========================================================================
template<int K0>
__global__ __launch_bounds__(TPB, 2)
void fused_kernel(const int* __restrict__ rs, const int* __restrict__ col,
                  const float* __restrict__ srcdat, int nvar,
                  const float* __restrict__ xg,
                  const float* __restrict__ W0, const float* __restrict__ b0,
                  const float* __restrict__ uW1, const float* __restrict__ ub1,
                  const float* __restrict__ uW2, const float* __restrict__ ub2,
                  const float* __restrict__ uW3, const float* __restrict__ ub3,
                  const float* __restrict__ pW1, const float* __restrict__ pb1,
                  const float* __restrict__ pW2, const float* __restrict__ pb2,
                  const float* __restrict__ pW3, const float* __restrict__ pb3,
                  float* __restrict__ state_g, float* __restrict__ outg, int n)
{
    __shared__ float act[BM * AS];
    __shared__ float wbuf[2 * 2048];
    __shared__ float ldeg[BM];

    const int tid = threadIdx.x;
    const long base = (long)blockIdx.x * BM;
    const int nvar2 = 2 * nvar;
    const int wave = tid >> 6;
    const int lane = tid & 63;

    // ---- CSR gather into act[:, 0:K0]; deg -> ldeg
    if constexpr (K0 == 64) {
        for (int i = 0; i < 8; i++) {
            int node = wave * 8 + i;
            long g = base + node;
            int d0 = 0, d1 = 0;
            if (g < n) { d0 = rs[g]; d1 = rs[g + 1]; }
            float acc = 0.0f;
            int e = d0;
            for (; e + 4 <= d1; e += 4) {
                int s0 = col[e], s1 = col[e + 1], s2 = col[e + 2], s3 = col[e + 3];
                float a0 = (s0 < nvar2) ? srcdat[(long)s0 * 64 + lane] : 0.0f;
                float a1 = (s1 < nvar2) ? srcdat[(long)s1 * 64 + lane] : 0.0f;
                float a2 = (s2 < nvar2) ? srcdat[(long)s2 * 64 + lane] : 0.0f;
                float a3 = (s3 < nvar2) ? srcdat[(long)s3 * 64 + lane] : 0.0f;
                acc += a0 + a1 + a2 + a3;
            }
            for (; e < d1; e++) {
                int s = col[e];
                if (s < nvar2) acc += srcdat[(long)s * 64 + lane];
            }
            act[node * AS + lane] = acc;
            if (lane == 0) ldeg[node] = (float)(d1 - d0);
        }
    } else {
        const int f = lane & 15, sub = lane >> 4;
        for (int i = 0; i < 2; i++) {
            int node = wave * 8 + i * 4 + sub;
            long g = base + node;
            int d0 = 0, d1 = 0;
            if (g < n) { d0 = rs[g]; d1 = rs[g + 1]; }
            float acc = 0.0f;
            int e = d0;
            for (; e + 2 <= d1; e += 2) {
                int s0 = col[e], s1 = col[e + 1];
                float a0 = 0.0f, a1 = 0.0f;
                if (s0 < nvar2) {
                    a0 = srcdat[(long)((s0 < nvar) ? s0 : s0 - nvar) * 16 + f];
                    if (s0 >= nvar) a0 = -a0;
                }
                if (s1 < nvar2) {
                    a1 = srcdat[(long)((s1 < nvar) ? s1 : s1 - nvar) * 16 + f];
                    if (s1 >= nvar) a1 = -a1;
                }
                acc += a0 + a1;
            }
            for (; e < d1; e++) {
                int s = col[e];
                if (s < nvar2) {
                    float a = srcdat[(long)((s < nvar) ? s : s - nvar) * 16 + f];
                    acc += (s < nvar) ? a : -a;
                }
            }
            act[node * AS + f] = acc;
            if (f == 0) ldeg[node] = (float)(d1 - d0);
        }
    }
    __syncthreads();

    // ---- layer0: msg = gather@W0 + deg*b0 (reads cols 0:K0, writes 0:64)
    gemm_layer<2>(act, W0, b0, ldeg, wbuf, K0, K0, false, nullptr, base, n);

    // stage x -> cols 64..66, zero col 67 (ordered by next layer's prologue barrier)
    for (int idx = tid; idx < BM * 3; idx += TPB) {
        int node = idx / 3, j = idx % 3;
        float v = (base + node < n) ? xg[(base + node) * 3 + j] : 0.0f;
        act[node * AS + 64 + j] = v;
    }
    if (tid < BM) act[tid * AS + 67] = 0.0f;

    // ---- update MLP
    gemm_layer<4>(act, uW1, ub1, nullptr, wbuf, 67, 68, true, nullptr, base, n);
    gemm_layer<4>(act, uW2, ub2, nullptr, wbuf, 128, 128, true, nullptr, base, n);
    gemm_layer<2>(act, uW3, ub3, nullptr, wbuf, 128, 128, false, state_g, base, n);

    // ---- predictor MLP
    gemm_layer<4>(act, pW1, pb1, nullptr, wbuf, 64, 64, true, nullptr, base, n);
    gemm_layer<4>(act, pW2, pb2, nullptr, wbuf, 128, 128, true, nullptr, base, n);

    // ---- predictor layer3: 128 -> 2
    for (int i = tid; i < 64; i += TPB)
        ((float4*)wbuf)[i] = ((const float4*)pW3)[i];
    __syncthreads();
    if (tid < 128) {
        int r = tid >> 1, c = tid & 1;
        float acc = pb3[c];
        for (int k = 0; k < 128; k += 4) {
            float4 a = *(const float4*)(act + r * AS + k);
            acc = fmaf(a.x, wbuf[(k + 0) * 2 + c], acc);
            acc = fmaf(a.y, wbuf[(k + 1) * 2 + c], acc);
            acc = fmaf(a.z, wbuf[(k + 2) * 2 + c], acc);
            acc = fmaf(a.w, wbuf[(k + 3) * 2 + c], acc);
        }
        if (base + r < n) outg[(base + r) * 2 + c] = acc;
    }
}

// ===========================================================================
extern "C" void kernel_launch(void* const* d_in, const int* in_sizes, int n_in,
                              void* d_out, int out_size, void* d_ws, size_t ws_size,
                              hipStream_t stream)
{
    const float* x    = (const float*)d_in[0];
    const int*   ei   = (const int*)d_in[1];
    // d_in[2] = gate_type: fixed ordering [VAR*nvar, NEGVAR*nvar, CLAUSE*ncla]
    const float* posr = (const float*)d_in[3];
    const float* Wr   = (const float*)d_in[4];
    const float* br   = (const float*)d_in[5];
    const float* Wc   = (const float*)d_in[6];
    const float* bc   = (const float*)d_in[7];
    const float* uW1  = (const float*)d_in[8];
    const float* ub1  = (const float*)d_in[9];
    const float* uW2  = (const float*)d_in[10];
    const float* ub2  = (const float*)d_in[11];
    const float* uW3  = (const float*)d_in[12];
    const float* ub3  = (const float*)d_in[13];
    const float* pW1  = (const float*)d_in[14];
    const float* pb1  = (const float*)d_in[15];
    const float* pW2  = (const float*)d_in[16];
    const float* pb2  = (const float*)d_in[17];
    const float* pW3  = (const float*)d_in[18];
    const float* pb3  = (const float*)d_in[19];

    const int N     = in_sizes[0] / 3;
    const int E     = in_sizes[1] / 2;
    const int nvar  = in_sizes[3] / 16;
    const int nvar2 = 2 * nvar;
    const int ncla  = N - nvar2;

    // workspace carve-out
    int* cnt    = (int*)d_ws;              // [N]
    int* rs     = cnt + N;                 // [N+1]
    int* cursor = rs + N + 1;              // [N]
    int* part   = cursor + N;              // [2048]
    int* col    = part + 2048;             // [E]
    size_t foff = ((size_t)(col + E - (int*)d_ws) + 3) & ~(size_t)3;
    float* state = (float*)d_ws + foff;    // [2nvar*64]

    hipMemsetAsync(cnt, 0, (size_t)N * sizeof(int), stream);

    const int nb = (N + 2047) / 2048;
    count_kernel<<<(E + 255) / 256, 256, 0, stream>>>(ei, cnt, E);
    scan_blocks<<<nb, 256, 0, stream>>>(cnt, rs, part, N);
    scan_part<<<1, 256, 0, stream>>>(part, nb);
    scan_fixup<<<(N + 255) / 256, 256, 0, stream>>>(rs, cursor, part, N, E);
    scatter_kernel<<<(E + 255) / 256, 256, 0, stream>>>(ei, cursor, col, E);

    {   // var + negvar partitions (gather pos_random via CSR)
        int blocks = (nvar2 + BM - 1) / BM;
        fused_kernel<16><<<blocks, TPB, 0, stream>>>(
            rs, col, posr, nvar, x, Wr, br,
            uW1, ub1, uW2, ub2, uW3, ub3,
            pW1, pb1, pW2, pb2, pW3, pb3,
            state, (float*)d_out, nvar2);
    }

    {   // clause partition (gather state via CSR, rows offset by 2nvar)
        int blocks = (ncla + BM - 1) / BM;
        fused_kernel<64><<<blocks, TPB, 0, stream>>>(
            rs + nvar2, col, state, nvar, x + (size_t)nvar2 * 3, Wc, bc,
            uW1, ub1, uW2, ub2, uW3, ub3,
            pW1, pb1, pW2, pb2, pW3, pb3,
            nullptr, (float*)d_out + (size_t)nvar2 * 2, ncla);
    }
}

// Round 6
// 1559.065 us; speedup vs baseline: 3.3270x; 2.8346x over previous
//
#include <hip/hip_runtime.h>

#define TPB 512
#define BM 128
#define AS 128   // activation row stride in floats

// ===========================================================================
// CSR build: count -> block scan -> fixup -> scatter. Rebuilt every call.
// ===========================================================================
__global__ void count_kernel(const int* __restrict__ ei, int* __restrict__ cnt, int E)
{
    int e = blockIdx.x * blockDim.x + threadIdx.x;
    if (e >= E) return;
    atomicAdd(cnt + ei[E + e], 1);
}

__global__ void scan_blocks(const int* __restrict__ cnt, int* __restrict__ rs,
                            int* __restrict__ part, int N)
{
    __shared__ int sums[256];
    int t = threadIdx.x;
    int base = blockIdx.x * 2048 + t * 8;
    int v[8], s = 0;
#pragma unroll
    for (int i = 0; i < 8; i++) { int idx = base + i; v[i] = (idx < N) ? cnt[idx] : 0; s += v[i]; }
    sums[t] = s;
    __syncthreads();
    for (int off = 1; off < 256; off <<= 1) {
        int x = (t >= off) ? sums[t - off] : 0;
        __syncthreads();
        if (t >= off) sums[t] += x;
        __syncthreads();
    }
    int run = (t == 0) ? 0 : sums[t - 1];
#pragma unroll
    for (int i = 0; i < 8; i++) { int idx = base + i; if (idx < N) rs[idx] = run; run += v[i]; }
    if (t == 255) part[blockIdx.x] = sums[255];
}

__global__ void scan_part(int* __restrict__ part, int nb)
{
    __shared__ int sums[256];
    int t = threadIdx.x;
    int base = t * 8;
    int v[8], s = 0;
#pragma unroll
    for (int i = 0; i < 8; i++) { int idx = base + i; v[i] = (idx < nb) ? part[idx] : 0; s += v[i]; }
    sums[t] = s;
    __syncthreads();
    for (int off = 1; off < 256; off <<= 1) {
        int x = (t >= off) ? sums[t - off] : 0;
        __syncthreads();
        if (t >= off) sums[t] += x;
        __syncthreads();
    }
    int run = (t == 0) ? 0 : sums[t - 1];
#pragma unroll
    for (int i = 0; i < 8; i++) { int idx = base + i; if (idx < nb) part[idx] = run; run += v[i]; }
}

__global__ void scan_fixup(int* __restrict__ rs, int* __restrict__ cursor,
                           const int* __restrict__ part, int N, int E)
{
    int i = blockIdx.x * blockDim.x + threadIdx.x;
    if (i < N) { int v = rs[i] + part[i >> 11]; rs[i] = v; cursor[i] = v; }
    if (i == 0) rs[N] = E;
}

__global__ void scatter_kernel(const int* __restrict__ ei, int* __restrict__ cursor,
                               int* __restrict__ col, int E)
{
    int e = blockIdx.x * blockDim.x + threadIdx.x;
    if (e >= E) return;
    int d = ei[E + e];
    int p = atomicAdd(cursor + d, 1);
    col[p] = ei[e];
}

// ===========================================================================
// FMA over one 8KB weight chunk in LDS. 128-row tile, 8 rows/thread in two
// 4-row halves (caps live registers ~64). acc[8][CPT] indices compile-time.
// ===========================================================================
template<int CPT>
__device__ __forceinline__ void chunk_fma(const float* __restrict__ act,
                                          const float* __restrict__ wc,
                                          int kb, int rows, int r0, int c0,
                                          float (&acc)[8][CPT])
{
    constexpr int C = CPT * 32;
    for (int k = 0; k < rows; k += 4) {
#pragma unroll
        for (int h = 0; h < 2; h++) {
            const int rr = r0 + h * 4;
            float4 a0 = *(const float4*)(act + (rr + 0) * AS + kb + k);
            float4 a1 = *(const float4*)(act + (rr + 1) * AS + kb + k);
            float4 a2 = *(const float4*)(act + (rr + 2) * AS + kb + k);
            float4 a3 = *(const float4*)(act + (rr + 3) * AS + kb + k);
#pragma unroll
            for (int kk = 0; kk < 4; kk++) {
                float b[CPT];
                if (CPT == 4) {
                    float4 bv = *(const float4*)(wc + (k + kk) * C + c0);
                    b[0] = bv.x; b[1] = bv.y; b[2] = bv.z; b[3] = bv.w;
                } else {
                    float2 bv = *(const float2*)(wc + (k + kk) * C + c0);
                    b[0] = bv.x; b[1] = bv.y;
                }
                float av[4];
                av[0] = ((const float*)&a0)[kk];
                av[1] = ((const float*)&a1)[kk];
                av[2] = ((const float*)&a2)[kk];
                av[3] = ((const float*)&a3)[kk];
#pragma unroll
                for (int i = 0; i < 4; i++)
#pragma unroll
                    for (int j = 0; j < CPT; j++)
                        acc[h * 4 + i][j] = fmaf(av[i], b[j], acc[h * 4 + i][j]);
            }
        }
    }
}

// ===========================================================================
// In-place GEMM layer, round-3-proven staging: stage 8KB chunk -> sync ->
// fma -> sync. No prefetch registers (rounds 4/5 proved they spill here).
//   act[r][0:C] = f(sum_k act[r][k]*W[k][c] + scale(r)*bias[c])
// ===========================================================================
template<int CPT>
__device__ __forceinline__ void gemm_layer(
    float* __restrict__ act, const float* __restrict__ Wg,
    const float* __restrict__ bias_g, const float* __restrict__ ldeg,
    float* __restrict__ wbuf,                 // 2048 floats (8KB)
    int K_real, int K_pad, bool relu,
    float* __restrict__ state_g, long base, int n)
{
    constexpr int C = CPT * 32;
    constexpr int RPC = 2048 / C;             // rows per 8KB chunk
    const int tid = threadIdx.x;
    const int tx = tid & 31;
    const int ty = tid >> 5;
    const int r0 = ty * 8;
    const int c0 = tx * CPT;
    const int nc = (K_pad + RPC - 1) / RPC;

    // per-thread 16B slice of the chunk
    const int fo = tid * 4;
    const int lr = fo / C;
    const int lc = fo - lr * C;

    float acc[8][CPT];
#pragma unroll
    for (int i = 0; i < 8; i++)
#pragma unroll
        for (int j = 0; j < CPT; j++) acc[i][j] = 0.0f;

    for (int c = 0; c < nc; ++c) {
        const int kb = c * RPC;
        int rows = K_pad - kb; if (rows > RPC) rows = RPC;
        // stage chunk (zero rows beyond K_real)
        {
            int gk = kb + lr;
            float4 v = make_float4(0.f, 0.f, 0.f, 0.f);
            if (gk < K_real) v = *(const float4*)(Wg + (long)gk * C + lc);
            *(float4*)(wbuf + fo) = v;
        }
        __syncthreads();
        chunk_fma<CPT>(act, wbuf, kb, rows, r0, c0, acc);
        __syncthreads();
    }

    // all act reads done (barrier above) -> write outputs in place
#pragma unroll
    for (int i = 0; i < 8; i++) {
        int r = r0 + i;
        float scale = ldeg ? ldeg[r] : 1.0f;
        float vv[CPT];
#pragma unroll
        for (int j = 0; j < CPT; j++) {
            float v = acc[i][j] + scale * bias_g[c0 + j];
            if (relu) v = fmaxf(v, 0.0f);
            vv[j] = v;
        }
        if (CPT == 4) *(float4*)(act + r * AS + c0) = make_float4(vv[0], vv[1], vv[2], vv[3]);
        else          *(float2*)(act + r * AS + c0) = make_float2(vv[0], vv[1]);
        if (state_g != nullptr && base + r < n) {
            if (CPT == 4) *(float4*)(state_g + (base + r) * 64 + c0) = make_float4(vv[0], vv[1], vv[2], vv[3]);
            else          *(float2*)(state_g + (base + r) * 64 + c0) = make_float2(vv[0], vv[1]);
        }
    }
    __syncthreads();
}

// ===========================================================================
// Fused per-128-node-tile: CSR gather -> layer0 -> update MLP -> predictor.
// LDS = 64KB act + 8KB wbuf + 0.5KB ldeg -> 2 blocks/CU.
// launch_bounds(512,4): VGPR cap 128 (16 waves/CU); 8-row tile fits ~100.
// ===========================================================================
template<int K0>
__global__ __launch_bounds__(TPB, 4)
void fused_kernel(const int* __restrict__ rs, const int* __restrict__ col,
                  const float* __restrict__ srcdat, int nvar,
                  const float* __restrict__ xg,
                  const float* __restrict__ W0, const float* __restrict__ b0,
                  const float* __restrict__ uW1, const float* __restrict__ ub1,
                  const float* __restrict__ uW2, const float* __restrict__ ub2,
                  const float* __restrict__ uW3, const float* __restrict__ ub3,
                  const float* __restrict__ pW1, const float* __restrict__ pb1,
                  const float* __restrict__ pW2, const float* __restrict__ pb2,
                  const float* __restrict__ pW3, const float* __restrict__ pb3,
                  float* __restrict__ state_g, float* __restrict__ outg, int n)
{
    __shared__ float act[BM * AS];
    __shared__ float wbuf[2048];
    __shared__ float ldeg[BM];

    const int tid = threadIdx.x;
    const long base = (long)blockIdx.x * BM;
    const int nvar2 = 2 * nvar;
    const int wave = tid >> 6;
    const int lane = tid & 63;

    // ---- CSR gather into act[:, 0:K0]; deg -> ldeg
    if constexpr (K0 == 64) {
        for (int i = 0; i < 16; i++) {
            int node = wave * 16 + i;
            long g = base + node;
            int d0 = 0, d1 = 0;
            if (g < n) { d0 = rs[g]; d1 = rs[g + 1]; }
            float acc = 0.0f;
            int e = d0;
            for (; e + 4 <= d1; e += 4) {
                int s0 = col[e], s1 = col[e + 1], s2 = col[e + 2], s3 = col[e + 3];
                float a0 = (s0 < nvar2) ? srcdat[(long)s0 * 64 + lane] : 0.0f;
                float a1 = (s1 < nvar2) ? srcdat[(long)s1 * 64 + lane] : 0.0f;
                float a2 = (s2 < nvar2) ? srcdat[(long)s2 * 64 + lane] : 0.0f;
                float a3 = (s3 < nvar2) ? srcdat[(long)s3 * 64 + lane] : 0.0f;
                acc += a0 + a1 + a2 + a3;
            }
            for (; e < d1; e++) {
                int s = col[e];
                if (s < nvar2) acc += srcdat[(long)s * 64 + lane];
            }
            act[node * AS + lane] = acc;
            if (lane == 0) ldeg[node] = (float)(d1 - d0);
        }
    } else {
        const int f = lane & 15, sub = lane >> 4;
        for (int i = 0; i < 4; i++) {
            int node = wave * 16 + i * 4 + sub;
            long g = base + node;
            int d0 = 0, d1 = 0;
            if (g < n) { d0 = rs[g]; d1 = rs[g + 1]; }
            float acc = 0.0f;
            int e = d0;
            for (; e + 2 <= d1; e += 2) {
                int s0 = col[e], s1 = col[e + 1];
                float a0 = 0.0f, a1 = 0.0f;
                if (s0 < nvar2) {
                    a0 = srcdat[(long)((s0 < nvar) ? s0 : s0 - nvar) * 16 + f];
                    if (s0 >= nvar) a0 = -a0;
                }
                if (s1 < nvar2) {
                    a1 = srcdat[(long)((s1 < nvar) ? s1 : s1 - nvar) * 16 + f];
                    if (s1 >= nvar) a1 = -a1;
                }
                acc += a0 + a1;
            }
            for (; e < d1; e++) {
                int s = col[e];
                if (s < nvar2) {
                    float a = srcdat[(long)((s < nvar) ? s : s - nvar) * 16 + f];
                    acc += (s < nvar) ? a : -a;
                }
            }
            act[node * AS + f] = acc;
            if (f == 0) ldeg[node] = (float)(d1 - d0);
        }
    }
    __syncthreads();

    // ---- layer0: msg = gather@W0 + deg*b0 (reads cols 0:K0, writes 0:64)
    gemm_layer<2>(act, W0, b0, ldeg, wbuf, K0, K0, false, nullptr, base, n);

    // stage x -> cols 64..66, zero col 67 (ordered by next layer's stage-sync)
    for (int idx = tid; idx < BM * 3; idx += TPB) {
        int node = idx / 3, j = idx % 3;
        float v = (base + node < n) ? xg[(base + node) * 3 + j] : 0.0f;
        act[node * AS + 64 + j] = v;
    }
    for (int idx = tid; idx < BM; idx += TPB) act[idx * AS + 67] = 0.0f;

    // ---- update MLP
    gemm_layer<4>(act, uW1, ub1, nullptr, wbuf, 67, 68, true, nullptr, base, n);
    gemm_layer<4>(act, uW2, ub2, nullptr, wbuf, 128, 128, true, nullptr, base, n);
    gemm_layer<2>(act, uW3, ub3, nullptr, wbuf, 128, 128, false, state_g, base, n);

    // ---- predictor MLP
    gemm_layer<4>(act, pW1, pb1, nullptr, wbuf, 64, 64, true, nullptr, base, n);
    gemm_layer<4>(act, pW2, pb2, nullptr, wbuf, 128, 128, true, nullptr, base, n);

    // ---- predictor layer3: 128 -> 2
    for (int i = tid; i < 64; i += TPB)
        ((float4*)wbuf)[i] = ((const float4*)pW3)[i];
    __syncthreads();
    if (tid < 256) {
        int r = tid >> 1, c = tid & 1;
        float acc = pb3[c];
        for (int k = 0; k < 128; k += 4) {
            float4 a = *(const float4*)(act + r * AS + k);
            acc = fmaf(a.x, wbuf[(k + 0) * 2 + c], acc);
            acc = fmaf(a.y, wbuf[(k + 1) * 2 + c], acc);
            acc = fmaf(a.z, wbuf[(k + 2) * 2 + c], acc);
            acc = fmaf(a.w, wbuf[(k + 3) * 2 + c], acc);
        }
        if (base + r < n) outg[(base + r) * 2 + c] = acc;
    }
}

// ===========================================================================
extern "C" void kernel_launch(void* const* d_in, const int* in_sizes, int n_in,
                              void* d_out, int out_size, void* d_ws, size_t ws_size,
                              hipStream_t stream)
{
    const float* x    = (const float*)d_in[0];
    const int*   ei   = (const int*)d_in[1];
    // d_in[2] = gate_type: fixed ordering [VAR*nvar, NEGVAR*nvar, CLAUSE*ncla]
    const float* posr = (const float*)d_in[3];
    const float* Wr   = (const float*)d_in[4];
    const float* br   = (const float*)d_in[5];
    const float* Wc   = (const float*)d_in[6];
    const float* bc   = (const float*)d_in[7];
    const float* uW1  = (const float*)d_in[8];
    const float* ub1  = (const float*)d_in[9];
    const float* uW2  = (const float*)d_in[10];
    const float* ub2  = (const float*)d_in[11];
    const float* uW3  = (const float*)d_in[12];
    const float* ub3  = (const float*)d_in[13];
    const float* pW1  = (const float*)d_in[14];
    const float* pb1  = (const float*)d_in[15];
    const float* pW2  = (const float*)d_in[16];
    const float* pb2  = (const float*)d_in[17];
    const float* pW3  = (const float*)d_in[18];
    const float* pb3  = (const float*)d_in[19];

    const int N     = in_sizes[0] / 3;
    const int E     = in_sizes[1] / 2;
    const int nvar  = in_sizes[3] / 16;
    const int nvar2 = 2 * nvar;
    const int ncla  = N - nvar2;

    // workspace carve-out
    int* cnt    = (int*)d_ws;              // [N]
    int* rs     = cnt + N;                 // [N+1]
    int* cursor = rs + N + 1;              // [N]
    int* part   = cursor + N;              // [2048]
    int* col    = part + 2048;             // [E]
    size_t foff = ((size_t)(col + E - (int*)d_ws) + 3) & ~(size_t)3;
    float* state = (float*)d_ws + foff;    // [2nvar*64]

    hipMemsetAsync(cnt, 0, (size_t)N * sizeof(int), stream);

    const int nb = (N + 2047) / 2048;
    count_kernel<<<(E + 255) / 256, 256, 0, stream>>>(ei, cnt, E);
    scan_blocks<<<nb, 256, 0, stream>>>(cnt, rs, part, N);
    scan_part<<<1, 256, 0, stream>>>(part, nb);
    scan_fixup<<<(N + 255) / 256, 256, 0, stream>>>(rs, cursor, part, N, E);
    scatter_kernel<<<(E + 255) / 256, 256, 0, stream>>>(ei, cursor, col, E);

    {   // var + negvar partitions (gather pos_random via CSR)
        int blocks = (nvar2 + BM - 1) / BM;
        fused_kernel<16><<<blocks, TPB, 0, stream>>>(
            rs, col, posr, nvar, x, Wr, br,
            uW1, ub1, uW2, ub2, uW3, ub3,
            pW1, pb1, pW2, pb2, pW3, pb3,
            state, (float*)d_out, nvar2);
    }

    {   // clause partition (gather state via CSR, rows offset by 2nvar)
        int blocks = (ncla + BM - 1) / BM;
        fused_kernel<64><<<blocks, TPB, 0, stream>>>(
            rs + nvar2, col, state, nvar, x + (size_t)nvar2 * 3, Wc, bc,
            uW1, ub1, uW2, ub2, uW3, ub3,
            pW1, pb1, pW2, pb2, pW3, pb3,
            nullptr, (float*)d_out + (size_t)nvar2 * 2, ncla);
    }
}